// Round 13
// baseline (180.511 us; speedup 1.0000x reference)
//
#include <hip/hip_runtime.h>
#include <hip/hip_bf16.h>
#include <stdint.h>
#include <stddef.h>

// MDCT as folded GEMM, FUSED: out[512, 32784] = D[512,512] . V[512, 32784]
// where V is never materialized — each gemm block folds its own B-tile
// from x:  V[c][j] = j<256:  x[g+j] - x[g+511-j]
//                   j>=256: x[g+j+256] + x[g+1279-j],  g = o*512-512.
// Precision: single fp16 product; absmax 0.03125 vs threshold 0.1069.
//
// R11: (a) REVERT R10 (96KB/1 block/CU regressed 40->57.5us: cross-block
// TLP beats pipeline depth). Back to R9: 64KB, 2 blocks/CU, depth-1
// counted vmcnt. (b) FUSE fold_x into B-staging: V's 34MB write + re-read
// round-trip and fold_x's ~16us wall disappear. The 4 m-blocks per nt are
// already same-XCD (grid swizzle) -> x re-reads L2-hit. Prior session's
// fused attempt serialized on register vmcnt waits; fixed here by issuing
// x-loads for tile k+1 at END of iter k-1 and waiting WAITV(4) only AFTER
// COMPUTE(k) — aged one full compute phase, A gld_lds left in flight.
// vmcnt ledger per iter k: [x(k+1):16 oldest, A(k+1):4] -> WAITV(4) drains
// x; after fold + XISSUE(k+2): [A(k+1):4 oldest, x(k+2):16] -> WAITV(16)
// drains A; BAR.
// R12: resubmit unchanged — R11's bench was an infra failure (container
// died twice; no compile/test/counter signal). Ledger re-audited, holds.

constexpr int N_ = 512;
constexpr int T_ = 2048;
constexpr int B_ = 16;
constexpr int LEN = N_ * T_;              // 2^20 per batch
constexpr int FRAMES = T_ + 1;            // 2049
constexpr int COLS = B_ * FRAMES;         // 32784
constexpr int NT_TILES = 257;
constexpr int COLS_PAD = NT_TILES * 128;  // 32896
constexpr int KF = 512;
constexpr int BK = 64;
constexpr int TILE_H = 128 * BK;          // elements per LDS buffer (8192)

typedef __attribute__((ext_vector_type(8))) _Float16 f16x8;
typedef __attribute__((ext_vector_type(4))) _Float16 f16x4;
typedef __attribute__((ext_vector_type(4))) float f32x4;

#define GLD16(gptr, lptr)                                                     \
  __builtin_amdgcn_global_load_lds(                                           \
      (const __attribute__((address_space(1))) unsigned int*)(gptr),          \
      (__attribute__((address_space(3))) unsigned int*)(lptr), 16, 0, 0)

// ---------------- Kernel 1: gather filter -> fp16 D -------------------------
__global__ void prep_filter(const float* __restrict__ f,
                            _Float16* __restrict__ D) {
  int idx = (blockIdx.x * 256 + threadIdx.x) * 4;
  int k = idx >> 9;
  int j = idx & 511;
  int t = (j < 256) ? j : (j + 256);
  const float4 v = *(const float4*)&f[k * 1024 + t];
  f16x4 h = {(_Float16)v.x, (_Float16)v.y, (_Float16)v.z, (_Float16)v.w};
  *(f16x4*)&D[k * KF + j] = h;
}

// ---------------- Kernel 2: fused C = D . fold(x) ---------------------------
// 128x128 tile, BK=64 static dbuf, depth-1 counted vmcnt, 4 waves (2x2 of
// 64x64), 16x16x32 f16. B-tile folded from x in-registers (2 threads/col:
// cl=tid>>1 owns col n0+cl, h=tid&1 owns 32 j's). A staged via gld_lds.
// Grid: 1024 = 8 XCD x 128; id -> xcd=id&7, sb=id>>3, m=sb&3,
// nt=(sb>>2)*8+xcd. Blocks 0..3 run tile (m=id, nt=256) as a second pass.
__global__ __launch_bounds__(256, 2) void gemm_fold(
    const float* __restrict__ x, const _Float16* __restrict__ D,
    float* __restrict__ out) {
  __shared__ __align__(16) _Float16 SMEM[4 * TILE_H];
  _Float16* const As0 = SMEM;
  _Float16* const Bs0 = SMEM + TILE_H;
  _Float16* const As1 = SMEM + 2 * TILE_H;
  _Float16* const Bs1 = SMEM + 3 * TILE_H;

  const int id = blockIdx.x;
  const int xcd = id & 7;
  const int sb = id >> 3;

  const int tid = threadIdx.x;
  const int wid = tid >> 6;
  const int lane = tid & 63;
  const int quad = lane >> 4;
  const int l16 = lane & 15;
  const int mw = (wid >> 1) * 64;
  const int nw = (wid & 1) * 64;
  const int cl = tid >> 1;   // local column 0..127
  const int h = tid & 1;     // 32-element half of the BK slice

#define WAITV(N) asm volatile("s_waitcnt vmcnt(" #N ")" ::: "memory")
#define WAITLGKM() asm volatile("s_waitcnt lgkmcnt(0)" ::: "memory")
#define BAR() __builtin_amdgcn_s_barrier()
#define SCHED0() __builtin_amdgcn_sched_barrier(0)

#define ASTAGE(AS, KT)                                                        \
  do {                                                                        \
    const int kb_ = (KT) * BK;                                                \
    _Pragma("unroll")                                                         \
    for (int it = 0; it < 4; ++it) {                                          \
      const int S_ = it * 256 + tid;                                          \
      const int r_ = S_ >> 3;                                                 \
      const int c_ = (S_ & 7) ^ (r_ & 7);                                     \
      GLD16(D + (size_t)(m0 + r_) * KF + kb_ + c_ * 8, &(AS)[S_ * 8]);        \
    }                                                                         \
  } while (0)

  // Issue the 16 float4 x-loads for tile KT into f0..f7 (fwd) / r0..r7
  // (rev, descending base). Segments are 32-float aligned; batch bounds
  // are multiples of 512 -> each segment fully in or out (one predicate).
#define XISSUE(KT)                                                            \
  do {                                                                        \
    const int kb_ = (KT) * BK;                                                \
    const int fb_ = gg + ((kb_ < 256) ? (kb_ + 32 * h)                        \
                                      : (kb_ + 256 + 32 * h));                \
    const int rb_ = gg + ((kb_ < 256) ? (480 - kb_ - 32 * h)                  \
                                      : (1248 - kb_ - 32 * h));               \
    f0 = f1 = f2 = f3 = f4 = f5 = f6 = f7 = (float4){0.f, 0.f, 0.f, 0.f};     \
    r0 = r1 = r2 = r3 = r4 = r5 = r6 = r7 = (float4){0.f, 0.f, 0.f, 0.f};     \
    if (cok && (unsigned)(fb_ - lo) <= (unsigned)(LEN - 32)) {                \
      const float4* p_ = (const float4*)(x + fb_);                            \
      f0 = p_[0]; f1 = p_[1]; f2 = p_[2]; f3 = p_[3];                         \
      f4 = p_[4]; f5 = p_[5]; f6 = p_[6]; f7 = p_[7];                         \
    }                                                                         \
    if (cok && (unsigned)(rb_ - lo) <= (unsigned)(LEN - 32)) {                \
      const float4* q_ = (const float4*)(x + rb_);                            \
      r0 = q_[0]; r1 = q_[1]; r2 = q_[2]; r3 = q_[3];                         \
      r4 = q_[4]; r5 = q_[5]; r6 = q_[6]; r7 = q_[7];                         \
    }                                                                         \
  } while (0)

  // One octet of fold outputs -> one swizzled ds_write_b128.
  // Mirror order matches the verified fold_x pattern (rev .w -> .x).
#define FW8(BP, G8, A0, A1, R1, R0, SG)                                       \
  do {                                                                        \
    f16x8 hh_;                                                                \
    hh_[0] = (_Float16)__builtin_fmaf(SG, (R1).w, (A0).x);                    \
    hh_[1] = (_Float16)__builtin_fmaf(SG, (R1).z, (A0).y);                    \
    hh_[2] = (_Float16)__builtin_fmaf(SG, (R1).y, (A0).z);                    \
    hh_[3] = (_Float16)__builtin_fmaf(SG, (R1).x, (A0).w);                    \
    hh_[4] = (_Float16)__builtin_fmaf(SG, (R0).w, (A1).x);                    \
    hh_[5] = (_Float16)__builtin_fmaf(SG, (R0).z, (A1).y);                    \
    hh_[6] = (_Float16)__builtin_fmaf(SG, (R0).y, (A1).z);                    \
    hh_[7] = (_Float16)__builtin_fmaf(SG, (R0).x, (A1).w);                    \
    const int sl_ = cl * 8 + ((4 * h + (G8)) ^ (cl & 7));                     \
    *(f16x8*)&(BP)[sl_ * 8] = hh_;                                            \
  } while (0)

  // Fold the 32 staged floats of tile KT and write them into BS with the
  // same slot/chunk swizzle the old gld_lds staging used (chunk cc at
  // slot cl*8 + (cc ^ (cl&7))). Chunks owned: 4h .. 4h+3.
#define FOLD_WRITE(BS, KT)                                                    \
  do {                                                                        \
    const float sg_ = ((KT) * BK < 256) ? -1.0f : 1.0f;                       \
    FW8((BS), 0, f0, f1, r7, r6, sg_);                                        \
    FW8((BS), 1, f2, f3, r5, r4, sg_);                                        \
    FW8((BS), 2, f4, f5, r3, r2, sg_);                                        \
    FW8((BS), 3, f6, f7, r1, r0, sg_);                                        \
  } while (0)

#define COMPUTE(AS, BS)                                                       \
  do {                                                                        \
    _Pragma("unroll")                                                         \
    for (int ko = 0; ko < 2; ++ko) {                                          \
      f16x8 af[4], bf[4];                                                     \
      _Pragma("unroll")                                                       \
      for (int i = 0; i < 4; ++i) {                                           \
        int ra_ = mw + i * 16 + l16;                                          \
        int rb_ = nw + i * 16 + l16;                                          \
        int ca_ = ko * 4 + quad;                                              \
        af[i] = *(const f16x8*)&(AS)[(ra_ * 8 + (ca_ ^ (ra_ & 7))) * 8];      \
        bf[i] = *(const f16x8*)&(BS)[(rb_ * 8 + (ca_ ^ (rb_ & 7))) * 8];      \
      }                                                                       \
      _Pragma("unroll")                                                       \
      for (int i = 0; i < 4; ++i)                                             \
        _Pragma("unroll")                                                     \
        for (int j = 0; j < 4; ++j)                                           \
          acc[i][j] = __builtin_amdgcn_mfma_f32_16x16x32_f16(af[i], bf[j],    \
                                                             acc[i][j],      \
                                                             0, 0, 0);        \
    }                                                                         \
  } while (0)

  // iter KT: compute tile KT; prep tile KT+1 (A via gld_lds, B via fold of
  // x-regs issued last iter); issue x for KT+2.
#define STEP(ASc, BSc, ASn, BSn, KT)                                          \
  do {                                                                        \
    if ((KT) < 7) ASTAGE(ASn, (KT) + 1);                                      \
    SCHED0();                                                                 \
    COMPUTE(ASc, BSc);                                                        \
    SCHED0();                                                                 \
    if ((KT) < 7) {                                                           \
      WAITV(4); /* drain x(KT+1), leave A(KT+1) in flight */                  \
      FOLD_WRITE(BSn, (KT) + 1);                                              \
      if ((KT) < 6) XISSUE((KT) + 2);                                         \
      WAITLGKM(); /* ds_writes visible before barrier */                      \
      if ((KT) < 6) { WAITV(16); } else { WAITV(0); } /* drain A(KT+1) */     \
      BAR();                                                                  \
    }                                                                         \
  } while (0)

  auto process = [&](int m0, int n0) {
    // Per-column fold geometry (per thread).
    const int c = n0 + cl;
    const bool cok = (c < COLS);
    const int b = (int)((unsigned)c / (unsigned)FRAMES);
    const int o = c - b * FRAMES;
    const int lo = b * LEN;
    const int gg = lo + o * N_ - N_;  // window start for this column

    float4 f0, f1, f2, f3, f4, f5, f6, f7;
    float4 r0, r1, r2, r3, r4, r5, r6, r7;

    f32x4 acc[4][4];
#pragma unroll
    for (int i = 0; i < 4; ++i)
#pragma unroll
      for (int j = 0; j < 4; ++j) acc[i][j] = (f32x4){0.f, 0.f, 0.f, 0.f};

    // Prologue: tile 0 (x regs + A), fold B0, issue x for tile 1.
    XISSUE(0);
    ASTAGE(As0, 0);
    WAITV(4);            // drain x(0); A(0) in flight
    FOLD_WRITE(Bs0, 0);
    XISSUE(1);           // outstanding: A(0):4 oldest, x(1):16
    WAITLGKM();
    WAITV(16);           // drain A(0)
    BAR();

    STEP(As0, Bs0, As1, Bs1, 0);
    STEP(As1, Bs1, As0, Bs0, 1);
    STEP(As0, Bs0, As1, Bs1, 2);
    STEP(As1, Bs1, As0, Bs0, 3);
    STEP(As0, Bs0, As1, Bs1, 4);
    STEP(As1, Bs1, As0, Bs0, 5);
    STEP(As0, Bs0, As1, Bs1, 6);
    STEP(As1, Bs1, As0, Bs0, 7);

    BAR();  // all waves done reading As*/Bs* before Ct overlay

    // ---------------- Epilogue (verified R8/R9) ----------------
    // acc[i][j][r] holds C[m0+mw+i*16+quad*4+r][n0+nw+j*16+l16].
    const int bs = n0 / FRAMES;
    const int os = n0 - bs * FRAMES;
    const bool fast = (os + 128 <= FRAMES) && (n0 + 128 <= COLS);

    if (fast) {
      float* Ct = (float*)SMEM;
#pragma unroll
      for (int i = 0; i < 4; ++i) {
#pragma unroll
        for (int j = 0; j < 4; ++j) {
          const int Lr0 = mw + i * 16 + quad * 4;
          const int Lc = nw + j * 16 + l16;
#pragma unroll
          for (int r = 0; r < 4; ++r) {
            const int row = Lr0 + r;
            Ct[row * 128 + (Lc ^ ((row & 12) << 2))] = acc[i][j][r];
          }
        }
      }
      __syncthreads();
      float* const obase = out + (size_t)bs * N_ * FRAMES + os;
#pragma unroll 4
      for (int it2 = 0; it2 < 32; ++it2) {
        const int row = wid * 32 + it2;
        const int sw = (row & 12) << 2;
        const int grow = m0 + row;
        const float v0 = Ct[row * 128 + (lane ^ sw)];
        const float v1 = Ct[row * 128 + ((64 + lane) ^ sw)];
        float* rp = obase + (size_t)grow * FRAMES;
        rp[lane] = v0;
        rp[64 + lane] = v1;
      }
    } else {
      // Straddle/tail tiles: verified scalar path.
#pragma unroll
      for (int i = 0; i < 4; ++i) {
#pragma unroll
        for (int j = 0; j < 4; ++j) {
          int col = n0 + nw + j * 16 + l16;
          if (col < COLS) {
            int bb = col / FRAMES;
            int oo = col - bb * FRAMES;
            int rowb = m0 + mw + i * 16 + quad * 4;
            float* op = out + (size_t)bb * N_ * FRAMES + (size_t)rowb * FRAMES + oo;
#pragma unroll
            for (int r = 0; r < 4; ++r) op[(size_t)r * FRAMES] = acc[i][j][r];
          }
        }
      }
    }
  };

  // Main tile: (m 0..3) x (nt 0..255) bijectively over 1024 blocks.
  process((sb & 3) * 128, ((sb >> 2) * 8 + xcd) * 128);

  // Second pass on blocks 0..3: leftover tiles (m=id, nt=256, 16 real cols).
  if (id < 4) {
    BAR();  // all waves done with SMEM (epilogue Ct reads) before restaging
    process(id * 128, 256 * 128);
  }

#undef STEP
#undef COMPUTE
#undef FOLD_WRITE
#undef FW8
#undef XISSUE
#undef ASTAGE
#undef WAITV
#undef WAITLGKM
#undef BAR
#undef SCHED0
}

// ---------------- Fallback: direct fp32 conv (if ws too small) --------------
__global__ void naive_conv(const float* __restrict__ x, const float* __restrict__ f,
                           float* __restrict__ out) {
  int col = blockIdx.x;
  int k = threadIdx.x;
  __shared__ float win[1024];
  int b = col / FRAMES;
  int o = col - b * FRAMES;
  const float* xb = x + (size_t)b * LEN;
  int g = o * N_ - N_;
  for (int t = threadIdx.x; t < 1024; t += 512) {
    int i = g + t;
    win[t] = (i >= 0 && i < LEN) ? xb[i] : 0.0f;
  }
  __syncthreads();
  float s = 0.0f;
  const float* fk = f + (size_t)k * 1024;
  for (int t = 0; t < 1024; ++t) s += win[t] * fk[t];
  out[(size_t)b * N_ * FRAMES + (size_t)k * FRAMES + o] = s;
}

extern "C" void kernel_launch(void* const* d_in, const int* in_sizes, int n_in,
                              void* d_out, int out_size, void* d_ws, size_t ws_size,
                              hipStream_t stream) {
  const float* x = (const float*)d_in[0];
  const float* f = (const float*)d_in[1];
  float* out = (float*)d_out;

  const size_t need = (size_t)512 * 512 * sizeof(_Float16);  // D only

  if (ws_size < need) {
    naive_conv<<<COLS, 512, 0, stream>>>(x, f, out);
    return;
  }

  _Float16* D = (_Float16*)d_ws;

  prep_filter<<<256, 256, 0, stream>>>(f, D);
  // Fused gemm: folds B from x on the fly; V never materialized.
  gemm_fold<<<1024, 256, 0, stream>>>(x, D, out);
}

// Round 14
// 164.494 us; speedup vs baseline: 1.0974x; 1.0974x over previous
//
#include <hip/hip_runtime.h>
#include <hip/hip_bf16.h>
#include <stdint.h>
#include <stddef.h>

// MDCT as folded GEMM, TWO-KERNEL structure (fusion double-refuted: R11/12
// fused = 96us vs 56us split — wave-level x coalescing collapses when 2
// threads/col own the fold; fold stays a separate coalesced pass).
//   out[512, 32784] = D[512,512] . V[512, 32784]
//   V[c][j] = j<256:  x[g+j] - x[g+511-j]
//             j>=256: x[g+j+256] + x[g+1279-j],   g = o*512 - 512 (per batch)
// Precision: single fp16 product; absmax 0.03125 vs threshold 0.1069.
//
// R13: revert to R8 base (session best 139.9us) + A-DIRECT-FROM-GLOBAL:
// D is 512KB, L2/L3-resident; A-fragments are 16B-aligned row chunks, so
// load them straight into regs one iter ahead (ar0/ar1 dbuf, static idx)
// instead of LDS-staging. Removes half the gld_lds, half the LDS writes,
// half the compute ds_reads. Ledger/iter k: issue B(k+1):4 + A(k+1):8;
// WAITV(12) drains A(k) regs (aged 1 iter); COMPUTE; WAITV(8) drains
// B(k+1) to LDS; BAR (A(k+1) stays in flight across it). Bs dbuf = 32KB;
// SMEM kept 64KB for Ct epilogue. Predict gemm 40 -> 32-35us, VGPR ~150.

constexpr int N_ = 512;
constexpr int T_ = 2048;
constexpr int B_ = 16;
constexpr int LEN = N_ * T_;              // 2^20 per batch
constexpr int FRAMES = T_ + 1;            // 2049
constexpr int COLS = B_ * FRAMES;         // 32784
constexpr int NT_TILES = 257;
constexpr int COLS_PAD = NT_TILES * 128;  // 32896
constexpr int KF = 512;
constexpr int BK = 64;
constexpr int TILE_H = 128 * BK;          // elements per LDS buffer (8192)

typedef __attribute__((ext_vector_type(8))) _Float16 f16x8;
typedef __attribute__((ext_vector_type(4))) _Float16 f16x4;
typedef __attribute__((ext_vector_type(4))) float f32x4;

#define GLD16(gptr, lptr)                                                     \
  __builtin_amdgcn_global_load_lds(                                           \
      (const __attribute__((address_space(1))) unsigned int*)(gptr),          \
      (__attribute__((address_space(3))) unsigned int*)(lptr), 16, 0, 0)

// ---------------- Kernel 1: gather filter -> fp16 D -------------------------
__global__ void prep_filter(const float* __restrict__ f,
                            _Float16* __restrict__ D) {
  int idx = (blockIdx.x * 256 + threadIdx.x) * 4;
  int k = idx >> 9;
  int j = idx & 511;
  int t = (j < 256) ? j : (j + 256);
  const float4 v = *(const float4*)&f[k * 1024 + t];
  f16x4 h = {(_Float16)v.x, (_Float16)v.y, (_Float16)v.z, (_Float16)v.w};
  *(f16x4*)&D[k * KF + j] = h;
}

// ---------------- Kernel 2: fold x -> V fp16, one wave per column -----------
// Lane l owns V[c][j0..j0+7]; fwd stream ascending contiguous, rev stream
// descending contiguous; one f16x8 store -> wave writes the whole 1KB col.
// XCD-swizzled (bijective, 8224=8*1028) so overlapping windows L2-hit.
__global__ void fold_x(const float* __restrict__ x, _Float16* __restrict__ V) {
  const int blk = (blockIdx.x & 7) * 1028 + (blockIdx.x >> 3);
  const int c = blk * 4 + (threadIdx.x >> 6);  // 4 columns per block
  const int l = threadIdx.x & 63;
  const bool mi = (l < 32);
  const int j0 = mi ? (l * 8) : (256 + (l - 32) * 8);
  const float sgn = mi ? -1.0f : 1.0f;
  float4 a0 = {0.f, 0.f, 0.f, 0.f}, a1 = {0.f, 0.f, 0.f, 0.f};
  float4 r0 = {0.f, 0.f, 0.f, 0.f}, r1 = {0.f, 0.f, 0.f, 0.f};
  if (c < COLS) {
    int b = (int)((unsigned)c / (unsigned)FRAMES);
    int o = c - b * FRAMES;
    const int lo = b * LEN;
    const int g = lo + o * N_ - N_;            // absolute window start
    const int fb = g + (mi ? j0 : (j0 + 256)); // fwd segment (8 floats)
    const int rb = g + (mi ? (504 - j0) : (1272 - j0)); // rev segment
    if ((unsigned)(fb - lo) <= (unsigned)(LEN - 8)) {
      a0 = *(const float4*)(x + fb);
      a1 = *(const float4*)(x + fb + 4);
    }
    if ((unsigned)(rb - lo) <= (unsigned)(LEN - 8)) {
      r0 = *(const float4*)(x + rb);
      r1 = *(const float4*)(x + rb + 4);
    }
  }
  f16x8 h;
  h[0] = (_Float16)__builtin_fmaf(sgn, r1.w, a0.x);
  h[1] = (_Float16)__builtin_fmaf(sgn, r1.z, a0.y);
  h[2] = (_Float16)__builtin_fmaf(sgn, r1.y, a0.z);
  h[3] = (_Float16)__builtin_fmaf(sgn, r1.x, a0.w);
  h[4] = (_Float16)__builtin_fmaf(sgn, r0.w, a1.x);
  h[5] = (_Float16)__builtin_fmaf(sgn, r0.z, a1.y);
  h[6] = (_Float16)__builtin_fmaf(sgn, r0.y, a1.z);
  h[7] = (_Float16)__builtin_fmaf(sgn, r0.x, a1.w);
  if (c < COLS_PAD) *(f16x8*)&V[(size_t)c * KF + j0] = h;
}

// ---------------- Kernel 3: C = D . V, fp16 MFMA ----------------------------
// 128x128 tile, 4 waves (2x2 of 64x64), 16x16x32 f16. B via gld_lds into
// 32KB Bs dbuf (counted vmcnt); A direct global->reg, 1 iter ahead.
// Grid: 1056; id -> xcd=id&7, s=id>>3, m=s&3, nt=(s>>2)*8+xcd; tail exits.
// Epilogue: swizzled LDS-transpose (R8-verified), Ct reuses 64KB SMEM.
__global__ __launch_bounds__(256, 2) void gemm_fold(
    const _Float16* __restrict__ D, const _Float16* __restrict__ V,
    float* __restrict__ out) {
  __shared__ __align__(16) _Float16 SMEM[4 * TILE_H];  // 64 KB (Ct overlay)
  _Float16* const Bs0 = SMEM;
  _Float16* const Bs1 = SMEM + TILE_H;

  const int id = blockIdx.x;
  const int xcd = id & 7;
  const int sb = id >> 3;
  const int nt = (sb >> 2) * 8 + xcd;
  if (nt >= NT_TILES) return;
  const int m0 = (sb & 3) * 128;
  const int n0 = nt * 128;

  // De-convoy (R8): anti-phase half the blocks.
  if ((id >> 8) & 1) {
    __builtin_amdgcn_s_sleep(15);
  }

  const int tid = threadIdx.x;
  const int wid = tid >> 6;
  const int lane = tid & 63;
  const int quad = lane >> 4;
  const int l16 = lane & 15;
  const int mw = (wid >> 1) * 64;
  const int nw = (wid & 1) * 64;

  // Per-lane base into D for A-fragments: row m0+mw+i*16+l16, col chunk
  // kt*64 + (ko*4+quad)*8. All offsets 16B-aligned.
  const _Float16* const Dp = D + (size_t)(m0 + mw + l16) * KF + quad * 8;

  f16x8 ar0[4][2], ar1[4][2];  // A-fragment double buffer (static idx only)
  f32x4 acc[4][4];
#pragma unroll
  for (int i = 0; i < 4; ++i)
#pragma unroll
    for (int j = 0; j < 4; ++j) acc[i][j] = (f32x4){0.f, 0.f, 0.f, 0.f};

#define WAITV(N) asm volatile("s_waitcnt vmcnt(" #N ")" ::: "memory")
#define BAR() __builtin_amdgcn_s_barrier()
#define SCHED0() __builtin_amdgcn_sched_barrier(0)

  // B-tile KT -> BS via 4 gld_lds/thread (slot/chunk swizzle as verified).
#define BSTAGE(BS, KT)                                                        \
  do {                                                                        \
    const int kb_ = (KT) * BK;                                                \
    _Pragma("unroll")                                                         \
    for (int it = 0; it < 4; ++it) {                                          \
      const int S_ = it * 256 + tid;                                          \
      const int r_ = S_ >> 3;                                                 \
      const int c_ = (S_ & 7) ^ (r_ & 7);                                     \
      GLD16(V + (size_t)(n0 + r_) * KF + kb_ + c_ * 8, &(BS)[S_ * 8]);        \
    }                                                                         \
  } while (0)

  // A-fragments for tile KT -> registers (8 x 16B loads/lane, no swizzle).
#define ALOAD(AR, KT)                                                         \
  do {                                                                        \
    _Pragma("unroll")                                                         \
    for (int i = 0; i < 4; ++i)                                               \
      _Pragma("unroll")                                                       \
      for (int ko = 0; ko < 2; ++ko)                                          \
        (AR)[i][ko] = *(const f16x8*)&Dp[(size_t)i * 16 * KF + ko * 32 +      \
                                         (KT) * 64];                          \
  } while (0)

#define COMPUTE(BS, AR)                                                       \
  do {                                                                        \
    _Pragma("unroll")                                                         \
    for (int ko = 0; ko < 2; ++ko) {                                          \
      f16x8 bf[4];                                                            \
      _Pragma("unroll")                                                       \
      for (int i = 0; i < 4; ++i) {                                           \
        int rb_ = nw + i * 16 + l16;                                          \
        int ca_ = ko * 4 + quad;                                              \
        bf[i] = *(const f16x8*)&(BS)[(rb_ * 8 + (ca_ ^ (rb_ & 7))) * 8];      \
      }                                                                       \
      _Pragma("unroll")                                                       \
      for (int i = 0; i < 4; ++i)                                             \
        _Pragma("unroll")                                                     \
        for (int j = 0; j < 4; ++j)                                           \
          acc[i][j] = __builtin_amdgcn_mfma_f32_16x16x32_f16((AR)[i][ko],     \
                                                             bf[j],          \
                                                             acc[i][j],      \
                                                             0, 0, 0);        \
    }                                                                         \
  } while (0)

  // Iter KT (0..6): issue B(KT+1)+A(KT+1); WAITV(12) drains A(KT) regs
  // (aged one iter); compute; WAITV(8) drains B(KT+1) into LDS; BAR
  // (A(KT+1) regs stay in flight across the barrier).
#define STEP(BSc, BSn, ARc, ARn, KT)                                          \
  do {                                                                        \
    BSTAGE(BSn, (KT) + 1);                                                    \
    ALOAD(ARn, (KT) + 1);                                                     \
    WAITV(12);                                                                \
    SCHED0();                                                                 \
    COMPUTE(BSc, ARc);                                                        \
    SCHED0();                                                                 \
    WAITV(8);                                                                 \
    BAR();                                                                    \
  } while (0)

  // Prologue: tile 0. Outstanding [B(0):4, A(0):8]; WAITV(8) drains B(0).
  BSTAGE(Bs0, 0);
  ALOAD(ar0, 0);
  WAITV(8);
  BAR();

  STEP(Bs0, Bs1, ar0, ar1, 0);
  STEP(Bs1, Bs0, ar1, ar0, 1);
  STEP(Bs0, Bs1, ar0, ar1, 2);
  STEP(Bs1, Bs0, ar1, ar0, 3);
  STEP(Bs0, Bs1, ar0, ar1, 4);
  STEP(Bs1, Bs0, ar1, ar0, 5);
  STEP(Bs0, Bs1, ar0, ar1, 6);
  // Iter 7: nothing left to stage; drain A(7) regs and compute.
  WAITV(0);
  SCHED0();
  COMPUTE(Bs1, ar1);
  SCHED0();
  BAR();  // all waves done reading Bs before Ct overlay

#undef STEP
#undef COMPUTE
#undef ALOAD
#undef BSTAGE

  // ---------------- Epilogue (verified R8) ----------------
  // acc[i][j][r] holds C[m0+mw+i*16+quad*4+r][n0+nw+j*16+l16].
  const int bs = n0 / FRAMES;
  const int os = n0 - bs * FRAMES;
  const bool fast = (os + 128 <= FRAMES) && (n0 + 128 <= COLS);

  if (fast) {
    // Swizzled dump: element (row,col) at col^sw, sw=(row&12)<<2 -> quads
    // split bank halves (2-way, free). Read Ct[row*128+(lane^sw)] ==
    // element (row,lane) — de-swizzle exactly once. Plain stores:
    // contiguous 256-B spans.
    float* Ct = (float*)SMEM;
#pragma unroll
    for (int i = 0; i < 4; ++i) {
#pragma unroll
      for (int j = 0; j < 4; ++j) {
        const int Lr0 = mw + i * 16 + quad * 4;
        const int Lc = nw + j * 16 + l16;
#pragma unroll
        for (int r = 0; r < 4; ++r) {
          const int row = Lr0 + r;
          Ct[row * 128 + (Lc ^ ((row & 12) << 2))] = acc[i][j][r];
        }
      }
    }
    __syncthreads();
    float* const obase = out + (size_t)bs * N_ * FRAMES + os;
#pragma unroll 4
    for (int it2 = 0; it2 < 32; ++it2) {
      const int row = wid * 32 + it2;     // local row 0..127
      const int sw = (row & 12) << 2;
      const int grow = m0 + row;          // global row < 512
      const float v0 = Ct[row * 128 + (lane ^ sw)];        // C[grow][os+lane]
      const float v1 = Ct[row * 128 + ((64 + lane) ^ sw)]; // C[grow][os+64+lane]
      float* rp = obase + (size_t)grow * FRAMES;
      rp[lane] = v0;
      rp[64 + lane] = v1;
    }
  } else {
    // Straddle/tail blocks: verified scalar path.
#pragma unroll
    for (int i = 0; i < 4; ++i) {
#pragma unroll
      for (int j = 0; j < 4; ++j) {
        int col = n0 + nw + j * 16 + l16;
        if (col < COLS) {
          int b = col / FRAMES;
          int o = col - b * FRAMES;
          int rowb = m0 + mw + i * 16 + quad * 4;
          float* op = out + (size_t)b * N_ * FRAMES + (size_t)rowb * FRAMES + o;
#pragma unroll
          for (int r = 0; r < 4; ++r) op[(size_t)r * FRAMES] = acc[i][j][r];
        }
      }
    }
  }
#undef WAITV
#undef BAR
#undef SCHED0
}

// ---------------- Fallback: direct fp32 conv (if ws too small) --------------
__global__ void naive_conv(const float* __restrict__ x, const float* __restrict__ f,
                           float* __restrict__ out) {
  int col = blockIdx.x;
  int k = threadIdx.x;
  __shared__ float win[1024];
  int b = col / FRAMES;
  int o = col - b * FRAMES;
  const float* xb = x + (size_t)b * LEN;
  int g = o * N_ - N_;
  for (int t = threadIdx.x; t < 1024; t += 512) {
    int i = g + t;
    win[t] = (i >= 0 && i < LEN) ? xb[i] : 0.0f;
  }
  __syncthreads();
  float s = 0.0f;
  const float* fk = f + (size_t)k * 1024;
  for (int t = 0; t < 1024; ++t) s += win[t] * fk[t];
  out[(size_t)b * N_ * FRAMES + (size_t)k * FRAMES + o] = s;
}

extern "C" void kernel_launch(void* const* d_in, const int* in_sizes, int n_in,
                              void* d_out, int out_size, void* d_ws, size_t ws_size,
                              hipStream_t stream) {
  const float* x = (const float*)d_in[0];
  const float* f = (const float*)d_in[1];
  float* out = (float*)d_out;

  const size_t elems_D = (size_t)512 * 512;
  const size_t elems_V = (size_t)COLS_PAD * KF;
  const size_t need = (elems_D + elems_V) * sizeof(_Float16);

  if (ws_size < need) {
    naive_conv<<<COLS, 512, 0, stream>>>(x, f, out);
    return;
  }

  _Float16* D = (_Float16*)d_ws;
  _Float16* V = D + elems_D;

  prep_filter<<<256, 256, 0, stream>>>(f, D);
  fold_x<<<COLS_PAD / 4, 256, 0, stream>>>(x, V);
  // Grid 1056 = 132*8: covers nt=0..256, m=0..3 (max id 1048); tail exits.
  gemm_fold<<<1056, 256, 0, stream>>>(D, V, out);
}

// Round 15
// 141.684 us; speedup vs baseline: 1.2740x; 1.1610x over previous
//
#include <hip/hip_runtime.h>
#include <hip/hip_bf16.h>
#include <stdint.h>
#include <stddef.h>

// MDCT as folded GEMM. out[512, 32784] = D[512,512] . V[512, 32784]
//   V[c][j] = j<256:  x[g+j] - x[g+511-j]
//             j>=256: x[g+j+256] + x[g+1279-j],   g = o*512 - 512 (per batch)
// Precision: single fp16 product; absmax 0.03125 vs threshold 0.1069.
//
// R14: REVERT to R8 verbatim (session best, 139.9us). R13's A-direct
// regressed (gemm 40->58us): compiler sank the plain-C++ A-prefetch loads
// to their use site (VGPR stayed 88, not ~150) and inserted its own
// vmcnt waits, serializing every iter. Third structural regression
// (depth-2, fusion, A-direct) — all reverted. fold_x measured at HBM
// roofline (98MB/16us = 6.1 TB/s). gemm ~40us, MfmaUtil 13-15% across
// six schedule variants. Remaining untried lever: 32x32 MFMA re-tile.

constexpr int N_ = 512;
constexpr int T_ = 2048;
constexpr int B_ = 16;
constexpr int LEN = N_ * T_;              // 2^20 per batch
constexpr int FRAMES = T_ + 1;            // 2049
constexpr int COLS = B_ * FRAMES;         // 32784
constexpr int NT_TILES = 257;
constexpr int COLS_PAD = NT_TILES * 128;  // 32896
constexpr int KF = 512;
constexpr int BK = 64;
constexpr int TILE_H = 128 * BK;          // elements per LDS buffer (8192)

typedef __attribute__((ext_vector_type(8))) _Float16 f16x8;
typedef __attribute__((ext_vector_type(4))) _Float16 f16x4;
typedef __attribute__((ext_vector_type(4))) float f32x4;

#define GLD16(gptr, lptr)                                                     \
  __builtin_amdgcn_global_load_lds(                                           \
      (const __attribute__((address_space(1))) unsigned int*)(gptr),          \
      (__attribute__((address_space(3))) unsigned int*)(lptr), 16, 0, 0)

// ---------------- Kernel 1: gather filter -> fp16 D -------------------------
__global__ void prep_filter(const float* __restrict__ f,
                            _Float16* __restrict__ D) {
  int idx = (blockIdx.x * 256 + threadIdx.x) * 4;
  int k = idx >> 9;
  int j = idx & 511;
  int t = (j < 256) ? j : (j + 256);
  const float4 v = *(const float4*)&f[k * 1024 + t];
  f16x4 h = {(_Float16)v.x, (_Float16)v.y, (_Float16)v.z, (_Float16)v.w};
  *(f16x4*)&D[k * KF + j] = h;
}

// ---------------- Kernel 2: fold x -> V fp16, one wave per column -----------
__global__ void fold_x(const float* __restrict__ x, _Float16* __restrict__ V) {
  const int blk = (blockIdx.x & 7) * 1028 + (blockIdx.x >> 3);
  const int c = blk * 4 + (threadIdx.x >> 6);  // 4 columns per block
  const int l = threadIdx.x & 63;
  const bool mi = (l < 32);
  const int j0 = mi ? (l * 8) : (256 + (l - 32) * 8);
  const float sgn = mi ? -1.0f : 1.0f;
  float4 a0 = {0.f, 0.f, 0.f, 0.f}, a1 = {0.f, 0.f, 0.f, 0.f};
  float4 r0 = {0.f, 0.f, 0.f, 0.f}, r1 = {0.f, 0.f, 0.f, 0.f};
  if (c < COLS) {
    int b = (int)((unsigned)c / (unsigned)FRAMES);
    int o = c - b * FRAMES;
    const int lo = b * LEN;
    const int g = lo + o * N_ - N_;            // absolute window start
    const int fb = g + (mi ? j0 : (j0 + 256)); // fwd segment (8 floats)
    const int rb = g + (mi ? (504 - j0) : (1272 - j0)); // rev segment
    if ((unsigned)(fb - lo) <= (unsigned)(LEN - 8)) {
      a0 = *(const float4*)(x + fb);
      a1 = *(const float4*)(x + fb + 4);
    }
    if ((unsigned)(rb - lo) <= (unsigned)(LEN - 8)) {
      r0 = *(const float4*)(x + rb);
      r1 = *(const float4*)(x + rb + 4);
    }
  }
  f16x8 h;
  h[0] = (_Float16)__builtin_fmaf(sgn, r1.w, a0.x);
  h[1] = (_Float16)__builtin_fmaf(sgn, r1.z, a0.y);
  h[2] = (_Float16)__builtin_fmaf(sgn, r1.y, a0.z);
  h[3] = (_Float16)__builtin_fmaf(sgn, r1.x, a0.w);
  h[4] = (_Float16)__builtin_fmaf(sgn, r0.w, a1.x);
  h[5] = (_Float16)__builtin_fmaf(sgn, r0.z, a1.y);
  h[6] = (_Float16)__builtin_fmaf(sgn, r0.y, a1.z);
  h[7] = (_Float16)__builtin_fmaf(sgn, r0.x, a1.w);
  if (c < COLS_PAD) *(f16x8*)&V[(size_t)c * KF + j0] = h;
}

// ---------------- Kernel 3: C = D . V, fp16 MFMA ----------------------------
// 128x128 tile, BK=64 static dbuf, counted-vmcnt 2-phase (R4), 4 waves
// (2x2 of 64x64), 16x16x32 f16. Grid: 1056; id -> xcd=id&7, s=id>>3,
// m=s&3, nt=(s>>2)*8+xcd. Epilogue: swizzled LDS-transpose (R7/R8).
__global__ __launch_bounds__(256, 2) void gemm_fold(
    const _Float16* __restrict__ D, const _Float16* __restrict__ V,
    float* __restrict__ out) {
  // One 64 KB block; k-loop uses 4 compile-time-disjoint 16 KB quarters.
  // Epilogue reuses the whole block as a swizzled 128x128 f32 tile.
  __shared__ __align__(16) _Float16 SMEM[4 * TILE_H];
  _Float16* const As0 = SMEM;
  _Float16* const Bs0 = SMEM + TILE_H;
  _Float16* const As1 = SMEM + 2 * TILE_H;
  _Float16* const Bs1 = SMEM + 3 * TILE_H;

  const int id = blockIdx.x;
  const int xcd = id & 7;
  const int sb = id >> 3;
  const int nt = (sb >> 2) * 8 + xcd;
  if (nt >= NT_TILES) return;
  const int m0 = (sb & 3) * 128;
  const int n0 = nt * 128;

  // De-convoy: anti-phase half the blocks so co-resident blocks overlap
  // staging with compute instead of hitting the same phase simultaneously.
  if ((id >> 8) & 1) {
    __builtin_amdgcn_s_sleep(15);  // ~960 cyc ~= half a k-iter
  }

  const int tid = threadIdx.x;
  const int wid = tid >> 6;
  const int lane = tid & 63;
  const int quad = lane >> 4;
  const int l16 = lane & 15;
  const int mw = (wid >> 1) * 64;
  const int nw = (wid & 1) * 64;

  f32x4 acc[4][4];
#pragma unroll
  for (int i = 0; i < 4; ++i)
#pragma unroll
    for (int j = 0; j < 4; ++j) acc[i][j] = (f32x4){0.f, 0.f, 0.f, 0.f};

#define STAGE(AS, BS, KT)                                                     \
  do {                                                                        \
    const int kb_ = (KT) * BK;                                                \
    _Pragma("unroll")                                                         \
    for (int it = 0; it < 4; ++it) {                                          \
      const int S_ = it * 256 + tid;   /* LDS slot = uniform base + lane */   \
      const int r_ = S_ >> 3;          /* tile row */                         \
      const int c_ = (S_ & 7) ^ (r_ & 7); /* swizzled global chunk */         \
      const int g_ = kb_ + c_ * 8;                                            \
      GLD16(D + (size_t)(m0 + r_) * KF + g_, &(AS)[S_ * 8]);                  \
      GLD16(V + (size_t)(n0 + r_) * KF + g_, &(BS)[S_ * 8]);                  \
    }                                                                         \
  } while (0)

#define COMPUTE(AS, BS)                                                       \
  do {                                                                        \
    _Pragma("unroll")                                                         \
    for (int ko = 0; ko < 2; ++ko) {                                          \
      f16x8 af[4], bf[4];                                                     \
      _Pragma("unroll")                                                       \
      for (int i = 0; i < 4; ++i) {                                           \
        int ra_ = mw + i * 16 + l16;                                          \
        int rb_ = nw + i * 16 + l16;                                          \
        int ca_ = ko * 4 + quad;                                              \
        af[i] = *(const f16x8*)&(AS)[(ra_ * 8 + (ca_ ^ (ra_ & 7))) * 8];      \
        bf[i] = *(const f16x8*)&(BS)[(rb_ * 8 + (ca_ ^ (rb_ & 7))) * 8];      \
      }                                                                       \
      _Pragma("unroll")                                                       \
      for (int i = 0; i < 4; ++i)                                             \
        _Pragma("unroll")                                                     \
        for (int j = 0; j < 4; ++j)                                           \
          acc[i][j] = __builtin_amdgcn_mfma_f32_16x16x32_f16(af[i], bf[j],    \
                                                             acc[i][j],      \
                                                             0, 0, 0);        \
    }                                                                         \
  } while (0)

#define WAITV(N) asm volatile("s_waitcnt vmcnt(" #N ")" ::: "memory")
#define BAR() __builtin_amdgcn_s_barrier()
#define SCHED0() __builtin_amdgcn_sched_barrier(0)

  // Prologue: fill buffer 0 (tile 0). 8 VMEM in flight.
  STAGE(As0, Bs0, 0);

  // WAITV(8): drain the oldest 8 (tile KT, aged one full iteration); the
  // 8 newest (tile KT+1) stay in flight across both barriers.
#define STEP(AScur, BScur, ASnxt, BSnxt, KT)                                  \
  do {                                                                        \
    if ((KT) < 7) {                                                           \
      STAGE(ASnxt, BSnxt, (KT) + 1);                                          \
      WAITV(8);                                                               \
    } else {                                                                  \
      WAITV(0);                                                               \
    }                                                                         \
    BAR();     /* collective: tile KT fully in LDS */                         \
    SCHED0();                                                                 \
    COMPUTE(AScur, BScur);                                                    \
    SCHED0();                                                                 \
    BAR();     /* all waves done reading -> buffer reusable */                \
  } while (0)

  STEP(As0, Bs0, As1, Bs1, 0);
  STEP(As1, Bs1, As0, Bs0, 1);
  STEP(As0, Bs0, As1, Bs1, 2);
  STEP(As1, Bs1, As0, Bs0, 3);
  STEP(As0, Bs0, As1, Bs1, 4);
  STEP(As1, Bs1, As0, Bs0, 5);
  STEP(As0, Bs0, As1, Bs1, 6);
  STEP(As1, Bs1, As0, Bs0, 7);

#undef STEP
#undef STAGE
#undef COMPUTE
#undef WAITV
#undef BAR
#undef SCHED0

  // ---------------- Epilogue ----------------
  // acc[i][j][r] holds C[m0 + mw + i*16 + quad*4 + r][n0 + nw + j*16 + l16].
  const int bs = n0 / FRAMES;
  const int os = n0 - bs * FRAMES;
  const bool fast = (os + 128 <= FRAMES) && (n0 + 128 <= COLS);

  if (fast) {
    // Swizzled dump: element (row,col) stored at col^sw, sw=(row&12)<<2.
    // Dump: sw==quad*16 -> quads {0,2}/{1,3} in opposite bank halves
    // (2-way, free). Read Ct[row*128 + (lane^sw)] == element (row,lane)
    // (de-swizzle happens HERE, exactly once); banks = perm of 0..63 ->
    // 2 lanes/bank (free). Store plainly: contiguous 256-B spans.
    float* Ct = (float*)SMEM;
#pragma unroll
    for (int i = 0; i < 4; ++i) {
#pragma unroll
      for (int j = 0; j < 4; ++j) {
        const int Lr0 = mw + i * 16 + quad * 4;
        const int Lc = nw + j * 16 + l16;
#pragma unroll
        for (int r = 0; r < 4; ++r) {
          const int row = Lr0 + r;
          Ct[row * 128 + (Lc ^ ((row & 12) << 2))] = acc[i][j][r];
        }
      }
    }
    __syncthreads();
    float* const obase = out + (size_t)bs * N_ * FRAMES + os;
#pragma unroll 4
    for (int it2 = 0; it2 < 32; ++it2) {
      const int row = wid * 32 + it2;     // local row 0..127
      const int sw = (row & 12) << 2;
      const int grow = m0 + row;          // global row < 512
      const float v0 = Ct[row * 128 + (lane ^ sw)];          // = C[grow][os+lane]
      const float v1 = Ct[row * 128 + ((64 + lane) ^ sw)];   // = C[grow][os+64+lane]
      float* rp = obase + (size_t)grow * FRAMES;
      rp[lane] = v0;
      rp[64 + lane] = v1;
    }
  } else {
    // Straddle/tail blocks (~64/1028): verified scalar path.
#pragma unroll
    for (int i = 0; i < 4; ++i) {
#pragma unroll
      for (int j = 0; j < 4; ++j) {
        int col = n0 + nw + j * 16 + l16;
        if (col < COLS) {
          int b = col / FRAMES;
          int o = col - b * FRAMES;
          int rowb = m0 + mw + i * 16 + quad * 4;
          float* op = out + (size_t)b * N_ * FRAMES + (size_t)rowb * FRAMES + o;
#pragma unroll
          for (int r = 0; r < 4; ++r) op[(size_t)r * FRAMES] = acc[i][j][r];
        }
      }
    }
  }
}

// ---------------- Fallback: direct fp32 conv (if ws too small) --------------
__global__ void naive_conv(const float* __restrict__ x, const float* __restrict__ f,
                           float* __restrict__ out) {
  int col = blockIdx.x;
  int k = threadIdx.x;
  __shared__ float win[1024];
  int b = col / FRAMES;
  int o = col - b * FRAMES;
  const float* xb = x + (size_t)b * LEN;
  int g = o * N_ - N_;
  for (int t = threadIdx.x; t < 1024; t += 512) {
    int i = g + t;
    win[t] = (i >= 0 && i < LEN) ? xb[i] : 0.0f;
  }
  __syncthreads();
  float s = 0.0f;
  const float* fk = f + (size_t)k * 1024;
  for (int t = 0; t < 1024; ++t) s += win[t] * fk[t];
  out[(size_t)b * N_ * FRAMES + (size_t)k * FRAMES + o] = s;
}

extern "C" void kernel_launch(void* const* d_in, const int* in_sizes, int n_in,
                              void* d_out, int out_size, void* d_ws, size_t ws_size,
                              hipStream_t stream) {
  const float* x = (const float*)d_in[0];
  const float* f = (const float*)d_in[1];
  float* out = (float*)d_out;

  const size_t elems_D = (size_t)512 * 512;
  const size_t elems_V = (size_t)COLS_PAD * KF;
  const size_t need = (elems_D + elems_V) * sizeof(_Float16);

  if (ws_size < need) {
    naive_conv<<<COLS, 512, 0, stream>>>(x, f, out);
    return;
  }

  _Float16* D = (_Float16*)d_ws;
  _Float16* V = D + elems_D;

  prep_filter<<<256, 256, 0, stream>>>(f, D);
  fold_x<<<COLS_PAD / 4, 256, 0, stream>>>(x, V);
  // Grid 1056 = 132*8: covers nt=0..256, m=0..3 (max id 1048); tail exits.
  gemm_fold<<<1056, 256, 0, stream>>>(D, V, out);
}